// Round 1
// 425.304 us; speedup vs baseline: 1.0028x; 1.0028x over previous
//
#include <hip/hip_runtime.h>

// RadarPillarFE: scatter-mean of (B,N,18) fp32 points into (B,18,256,256) fp32 BEV grid.
// R5: LDS-staged coalesced bin pass.
//   pass1 (bin):    stage 256 points (18KB) per block via contiguous float2 loads
//                   (coalesced, 512B/instr/wave) -> LDS -> each thread reads its xyz,
//                   mask -> voxel id -> slot = atomicAdd(per-VOXEL counter) -> store idx.
//   pass2 (reduce): one THREAD per voxel walks its own list serially, 18 reg accumulators,
//                   no atomics anywhere, writes means straight to output. (unchanged)

#define B_     8
#define NPTS   500000
#define F_     18
#define NX_    256
#define NY_    256
#define NVOX   (NX_ * NY_)         // 65536
#define BN     (B_ * NPTS)         // 4,000,000
#define NVOXT  (B_ * NVOX)         // 524,288 voxels total
#define CAP    32                  // slots per voxel (max expected occupancy ~25)

__global__ __launch_bounds__(256) void bin_kernel(const float* __restrict__ pts,
                                                  unsigned* __restrict__ cnt,
                                                  unsigned* __restrict__ list) {
    __shared__ float sh[256 * F_];                    // 18 KB -> 8 blocks/CU, 32 waves/CU
    const int tid = threadIdx.x;

    // Stage this block's 256 points (256*72B = 18KB) fully coalesced:
    // 9 rounds of contiguous float2 loads (each wave-instr covers 512B).
    const float2* __restrict__ gp =
        (const float2*)(pts + (size_t)blockIdx.x * (256 * F_));
    float2* sp = (float2*)sh;
#pragma unroll
    for (int k = 0; k < 9; ++k)
        sp[tid + 256 * k] = gp[tid + 256 * k];
    __syncthreads();

    float x = sh[tid * F_ + 0];
    float y = sh[tid * F_ + 1];
    float z = sh[tid * F_ + 2];
    bool ok = (x >= -51.2f) & (x <= 51.2f) &
              (y >= -51.2f) & (y <= 51.2f) &
              (z >= -5.0f)  & (z <= 3.0f);
    if (!ok) return;                                  // ~84.5% exit (after barrier: safe)

    int p  = blockIdx.x * 256 + tid;                  // grid exact: BN/256 = 15625
    int ix = min(max((int)((x + 51.2f) * 2.5f), 0), NX_ - 1);
    int iy = min(max((int)((y + 51.2f) * 2.5f), 0), NY_ - 1);
    int b  = p / NPTS;
    int vox = b * NVOX + iy * NX_ + ix;

    unsigned slot = atomicAdd(cnt + vox, 1u);         // the ONE atomic, low contention
    if (slot < CAP) list[(size_t)slot * NVOXT + vox] = (unsigned)p;  // transposed: coalesced reads
}

__global__ __launch_bounds__(256) void reduce_kernel(const float* __restrict__ pts,
                                                     const unsigned* __restrict__ cnt,
                                                     const unsigned* __restrict__ list,
                                                     float* __restrict__ out) {
    int v = blockIdx.x * 256 + threadIdx.x;           // voxel id; grid exact: NVOXT/256 = 2048
    int b   = v >> 16;                                // NVOX == 65536
    int pos = v & (NVOX - 1);

    unsigned c = min(cnt[v], (unsigned)CAP);

    float s[F_];
#pragma unroll
    for (int f = 0; f < F_; ++f) s[f] = 0.0f;

    for (unsigned i = 0; i < c; ++i) {
        unsigned p = list[(size_t)i * NVOXT + v];     // lane-coalesced across the wave
        const float2* rp = (const float2*)(pts + (size_t)p * F_);
#pragma unroll
        for (int j = 0; j < 9; ++j) {                 // 72B random gather, 8B-aligned loads
            float2 t = rp[j];
            s[2 * j]     += t.x;
            s[2 * j + 1] += t.y;
        }
    }

    float rcp = (c > 0) ? (1.0f / (float)c) : 0.0f;   // empty voxel -> exact 0, matches ref
    float* ob = out + (((size_t)b * F_) << 16) + pos; // (b, f, y, x), coalesced per-f stores
#pragma unroll
    for (int f = 0; f < F_; ++f) ob[(size_t)f << 16] = s[f] * rcp;
}

extern "C" void kernel_launch(void* const* d_in, const int* in_sizes, int n_in,
                              void* d_out, int out_size, void* d_ws, size_t ws_size,
                              hipStream_t stream) {
    const float* pts = (const float*)d_in[0];
    float* out = (float*)d_out;
    unsigned* cnt  = (unsigned*)d_ws;                 // 524,288 u32 = 2 MB
    unsigned* list = cnt + NVOXT;                     // CAP * 524,288 u32 = 67 MB

    hipMemsetAsync(cnt, 0, (size_t)NVOXT * sizeof(unsigned), stream);

    bin_kernel<<<BN / 256, 256, 0, stream>>>(pts, cnt, list);
    reduce_kernel<<<NVOXT / 256, 256, 0, stream>>>(pts, cnt, list, out);
}